// Round 6
// baseline (377.734 us; speedup 1.0000x reference)
//
#include <hip/hip_runtime.h>
#include <hip/hip_bf16.h>
#include <stdint.h>

// Problem constants: B=4, T=4096, L=4096, H=1024
#define BB 4
#define TT 4096
#define LL 4096
#define HH 1024

typedef __bf16 bf16x8 __attribute__((ext_vector_type(8)));
typedef float f32x4 __attribute__((ext_vector_type(4)));
typedef unsigned short us8v __attribute__((ext_vector_type(8)));
typedef unsigned short us;

// f32 -> bf16 bits, round-to-nearest-even
__device__ __forceinline__ unsigned short f2b(float f) {
    unsigned u = __builtin_bit_cast(unsigned, f);
    unsigned r = (u + 0x7FFFu + ((u >> 16) & 1u)) >> 16;
    return (unsigned short)r;
}
__device__ __forceinline__ float b2f(unsigned short u) {
    unsigned x = ((unsigned)u) << 16;
    return __builtin_bit_cast(float, x);
}

// async global->LDS, 16B/lane. LDS base wave-uniform (HW adds lane*16).
__device__ __forceinline__ void gload_lds16(const void* g, void* l) {
    __builtin_amdgcn_global_load_lds(
        (const __attribute__((address_space(1))) void*)(uintptr_t)g,
        (__attribute__((address_space(3))) void*)(uintptr_t)l,
        16, 0, 0);
}

// ---------------- f32 -> bf16 conversion ----------------
__global__ __launch_bounds__(256) void cvt_f32_bf16_k(const float4* __restrict__ src,
                                                      ushort4* __restrict__ dst, int n4) {
    int i = blockIdx.x * 256 + threadIdx.x;
    if (i >= n4) return;
    float4 v = src[i];
    ushort4 o;
    o.x = f2b(v.x); o.y = f2b(v.y); o.z = f2b(v.z); o.w = f2b(v.w);
    dst[i] = o;
}

// ---------------- f32 [1024][1024] -> bf16 transpose ----------------
__global__ __launch_bounds__(256) void transp_cvt_k(const float* __restrict__ src,
                                                    unsigned short* __restrict__ dst) {
    __shared__ float tile[32][33];
    const int lx = threadIdx.x & 31, ly = threadIdx.x >> 5;
    const int R = blockIdx.y * 32, C = blockIdx.x * 32;
#pragma unroll
    for (int rr = 0; rr < 4; rr++)
        tile[ly + rr * 8][lx] = src[(size_t)(R + ly + rr * 8) * HH + C + lx];
    __syncthreads();
#pragma unroll
    for (int rr = 0; rr < 4; rr++)
        dst[(size_t)(C + ly + rr * 8) * HH + R + lx] = f2b(tile[lx][ly + rr * 8]);
}

// ---------------- fold GEMM: both V-weight folds in one launch -----------------------
__global__ __launch_bounds__(256) void gemm_fold(const unsigned short* __restrict__ A,
                                                 const unsigned short* __restrict__ Bw,
                                                 unsigned short* __restrict__ dst1,
                                                 unsigned short* __restrict__ dst2) {
    const int K = 1024;
    __shared__ unsigned short ldsA[128 * 64];
    __shared__ unsigned short ldsB[128 * 64];

    const int tid = threadIdx.x;
    const int wave = tid >> 6, lane = tid & 63;
    const int m0 = blockIdx.y * 128, n0 = blockIdx.x * 128;
    const int wr = wave >> 1, wc = wave & 1;

    f32x4 acc[4][4];
#pragma unroll
    for (int m = 0; m < 4; m++)
#pragma unroll
        for (int n = 0; n < 4; n++) acc[m][n] = (f32x4)(0.0f);

    const unsigned short* Ab = A + (size_t)m0 * K;
    const unsigned short* Bb = Bw + (size_t)n0 * K;
    const int rbase = tid >> 3;
    const int col0 = (((tid & 7) ^ (rbase & 7)) << 3);

    for (int k0 = 0; k0 < K; k0 += 64) {
#pragma unroll
        for (int r = 0; r < 4; r++) {
            const int row = r * 32 + rbase;
            gload_lds16(Ab + (size_t)row * K + k0 + col0, &ldsA[r * 2048 + wave * 512]);
            gload_lds16(Bb + (size_t)row * K + k0 + col0, &ldsB[r * 2048 + wave * 512]);
        }
        __syncthreads();

        const int lr = lane & 15, hi = lane >> 4;
        const int sw = (lr & 7) << 4;
        const int c0 = ((hi * 16) ^ sw) >> 1;
        const int c1 = ((64 + hi * 16) ^ sw) >> 1;
        bf16x8 a0[4], a1[4], b0[4], b1[4];
#pragma unroll
        for (int m = 0; m < 4; m++) {
            const int row = (wr * 64 + m * 16 + lr) * 64;
            a0[m] = *reinterpret_cast<const bf16x8*>(&ldsA[row + c0]);
            a1[m] = *reinterpret_cast<const bf16x8*>(&ldsA[row + c1]);
        }
#pragma unroll
        for (int n = 0; n < 4; n++) {
            const int row = (wc * 64 + n * 16 + lr) * 64;
            b0[n] = *reinterpret_cast<const bf16x8*>(&ldsB[row + c0]);
            b1[n] = *reinterpret_cast<const bf16x8*>(&ldsB[row + c1]);
        }
#pragma unroll
        for (int m = 0; m < 4; m++)
#pragma unroll
            for (int n = 0; n < 4; n++)
                acc[m][n] = __builtin_amdgcn_mfma_f32_16x16x32_bf16(a0[m], b0[n], acc[m][n], 0, 0, 0);
#pragma unroll
        for (int m = 0; m < 4; m++)
#pragma unroll
            for (int n = 0; n < 4; n++)
                acc[m][n] = __builtin_amdgcn_mfma_f32_16x16x32_bf16(a1[m], b1[n], acc[m][n], 0, 0, 0);
        __syncthreads();
    }

    const int cc = lane & 15, cr = (lane >> 4) * 4;
#pragma unroll
    for (int m = 0; m < 4; m++)
#pragma unroll
        for (int n = 0; n < 4; n++)
#pragma unroll
            for (int r = 0; r < 4; r++) {
                const int row = m0 + wr * 64 + m * 16 + cr + r;
                const int col = n0 + wc * 64 + n * 16 + cc;
                unsigned short* base = (col < 1024) ? dst1 : dst2;
                base[(size_t)row * 1024 + (col & 1023)] = f2b(acc[m][n][r]);
            }
}

// ---------------- 256x256 GEMM, m201-style 4-phase quadrant pipeline -----------------
// 8 waves (2M x 4N), per-wave 128x64 = 8m x 4n frags of 16x16x32, BK=64 (kk0/kk1).
// LDS per buffer: A-lo[128x64] | A-hi | B-lo | B-hi (8192 elems each), x2 buffers =
// 128 KiB. Rows are 128 B; 16B-slot XOR swizzle slot^=(row&7) -> 0-conflict reads
// (2-way aliasing only, free). global_load_lds writes linearly; source pre-swizzled.
// Phases per tile t (quadrant = m-half x n-half):
//   P0: read A-quad-lo(8) + B n0-1(4); stage B-hi(t+1);  MFMA m0-3 x n0-1
//   P1: read B n2-3(4);                stage A-hi(t+1);  MFMA m0-3 x n2-3
//   P2: read A-quad-hi(8);             stage B-lo(t+2);  MFMA m4-7 x n2-3
//   P3: (no reads)                     stage A-lo(t+2);  MFMA m4-7 x n0-1; vmcnt(4)
// lo half-tiles staged 6 phases ahead, hi 3-4 phases ahead; single vmcnt(4)/tile
// drains exactly everything tile t+1 reads (leaves t+2's lo pair in flight).

#define BAR __builtin_amdgcn_s_barrier()
#define LGKM0SB { asm volatile("s_waitcnt lgkmcnt(0)" ::: "memory"); __builtin_amdgcn_sched_barrier(0); }
#define LGKM8 asm volatile("s_waitcnt lgkmcnt(8)" ::: "memory")
#define VMW4 asm volatile("s_waitcnt vmcnt(4)" ::: "memory")
#define VMW0 asm volatile("s_waitcnt vmcnt(0)" ::: "memory")

// stage one half-tile (128 rows x 64 k) into LDS element-offset dstE
#define STAGE_HT(dstE, G, grow, kcol) { \
    _Pragma("unroll") for (int i_ = 0; i_ < 2; i_++) \
        gload_lds16((G) + (size_t)((grow) + i_ * 64 + (tid >> 3)) * K + (kcol) + sc, \
                    lds + (dstE) + i_ * 4096 + wave * 512); }

#define RDA(cE, mh) { _Pragma("unroll") for (int m_ = 0; m_ < 4; m_++) { \
    a0[m_] = *reinterpret_cast<const bf16x8*>(lds + (cE) + offA0 + (mh) * 4096 + m_ * 1024); \
    a1[m_] = *reinterpret_cast<const bf16x8*>(lds + (cE) + offA1 + (mh) * 4096 + m_ * 1024); } }

#define RDB(cE, nh, r0, r1) { _Pragma("unroll") for (int n_ = 0; n_ < 2; n_++) { \
    r0[n_] = *reinterpret_cast<const bf16x8*>(lds + (cE) + offB0 + (nh) * 2048 + n_ * 1024); \
    r1[n_] = *reinterpret_cast<const bf16x8*>(lds + (cE) + offB1 + (nh) * 2048 + n_ * 1024); } }

#define MFMAQ(mh, nh, p0, p1) { __builtin_amdgcn_s_setprio(1); \
    _Pragma("unroll") for (int m_ = 0; m_ < 4; m_++) \
    _Pragma("unroll") for (int n_ = 0; n_ < 2; n_++) { \
        acc[(mh)*4+m_][(nh)*2+n_] = __builtin_amdgcn_mfma_f32_16x16x32_bf16(a0[m_], p0[n_], acc[(mh)*4+m_][(nh)*2+n_], 0, 0, 0); \
        acc[(mh)*4+m_][(nh)*2+n_] = __builtin_amdgcn_mfma_f32_16x16x32_bf16(a1[m_], p1[n_], acc[(mh)*4+m_][(nh)*2+n_], 0, 0, 0); } \
    __builtin_amdgcn_s_setprio(0); }

__global__ __launch_bounds__(512, 2) void gemm256(const us* __restrict__ A,
                                                  const us* __restrict__ Bw,
                                                  us* __restrict__ C,
                                                  int M, int N, int K, int gx) {
    __shared__ us lds[65536];   // 128 KB

    const int nwg = gridDim.x;
    const int bid = blockIdx.x;
    const int swz = (bid & 7) * (nwg >> 3) + (bid >> 3);   // grids multiple of 8
    const int bx = swz % gx, by = swz / gx;
    const int m0 = by * 256, n0 = bx * 256;

    const int tid = threadIdx.x;
    const int wave = tid >> 6, lane = tid & 63;
    const int wr = wave >> 2, wc = wave & 3;
    const int lr = lane & 15, hi = lane >> 4;

    // stage source pre-swizzle (rule #21): LDS byte = i*8192 + tid*16 (linear dest)
    const int sc = (((tid & 7) ^ ((tid >> 3) & 7)) << 3);   // element col within 64
    const us* Ablk = A + (size_t)m0 * K;
    const us* Bblk = Bw + (size_t)n0 * K;

    // ds_read offsets (elems within a buffer); frag step (m or n) = +1024
    const int offA0 = wr * 8192 + lr * 64 + ((hi ^ (lr & 7)) << 3);
    const int offA1 = wr * 8192 + lr * 64 + (((4 + hi) ^ (lr & 7)) << 3);
    const int offB0 = 16384 + (wc >> 1) * 8192 + (wc & 1) * 4096 + lr * 64 + ((hi ^ (lr & 7)) << 3);
    const int offB1 = 16384 + (wc >> 1) * 8192 + (wc & 1) * 4096 + lr * 64 + (((4 + hi) ^ (lr & 7)) << 3);

    f32x4 acc[8][4];
#pragma unroll
    for (int m = 0; m < 8; m++)
#pragma unroll
        for (int n = 0; n < 4; n++) acc[m][n] = (f32x4)(0.0f);

    bf16x8 a0[4], a1[4], bl0[2], bl1[2], bh0[2], bh1[2];

    // prologue: tile0 (all 4 half-tiles) + tile1's lo pair; drain tile0
    STAGE_HT(0,             Ablk, 0,   0);    // A-lo(0)
    STAGE_HT(16384,         Bblk, 0,   0);    // B-lo(0)
    STAGE_HT(8192,          Ablk, 128, 0);    // A-hi(0)
    STAGE_HT(24576,         Bblk, 128, 0);    // B-hi(0)
    STAGE_HT(32768 + 16384, Bblk, 0,   64);   // B-lo(1)
    STAGE_HT(32768,         Ablk, 0,   64);   // A-lo(1)
    VMW4;
    BAR;

    const int NT = K >> 6;
    for (int t = 0; t < NT; ++t) {
        const int c = (t & 1) << 15;          // buffer element offset (0 / 32768)
        const int cn = 32768 - c;
        const int k1 = (t + 1) << 6, k2 = (t + 2) << 6;
        const bool s1 = (t + 1 < NT), s2 = (t + 2 < NT);

        // P0
        RDA(c, 0);
        RDB(c, 0, bl0, bl1);
        if (s1) STAGE_HT(cn + 24576, Bblk, 128, k1);
        LGKM8;
        BAR; LGKM0SB;
        MFMAQ(0, 0, bl0, bl1);
        BAR;
        // P1
        RDB(c, 1, bh0, bh1);
        if (s1) STAGE_HT(cn + 8192, Ablk, 128, k1);
        BAR; LGKM0SB;
        MFMAQ(0, 1, bh0, bh1);
        BAR;
        // P2
        RDA(c, 1);
        if (s2) STAGE_HT(c + 16384, Bblk, 0, k2);
        BAR; LGKM0SB;
        MFMAQ(1, 1, bh0, bh1);
        BAR;
        // P3
        if (s2) STAGE_HT(c, Ablk, 0, k2);
        BAR;
        MFMAQ(1, 0, bl0, bl1);
        if (t < NT - 2) { VMW4; } else if (t == NT - 2) { VMW0; }
        BAR;
    }

    // C write: col = lane&15 (lr), row = hi*4 + reg
    const int crow0 = m0 + wr * 128 + hi * 4;
    const int ccol0 = n0 + wc * 64 + lr;
#pragma unroll
    for (int mi = 0; mi < 8; mi++)
#pragma unroll
        for (int ni = 0; ni < 4; ni++)
#pragma unroll
            for (int rr = 0; rr < 4; rr++)
                C[(size_t)(crow0 + mi * 16 + rr) * N + ccol0 + ni * 16] = f2b(acc[mi][ni][rr]);
}

// ---------------- windowed 3-way gated attention (batch-local, fused output) ----------
__device__ __forceinline__ float wave_sum(float v) {
#pragma unroll
    for (int off = 32; off > 0; off >>= 1) v += __shfl_xor(v, off, 64);
    return v;
}

__global__ __launch_bounds__(256) void attn_k(const unsigned short* __restrict__ Q,
                                              const unsigned short* __restrict__ KV,
                                              const int* __restrict__ adv_ids,
                                              const int* __restrict__ ptr_ids,
                                              const float* __restrict__ council,
                                              const float* __restrict__ gain_p,
                                              float* __restrict__ out) {
    const int wave = threadIdx.x >> 6, lane = threadIdx.x & 63;
    const int t = blockIdx.x * 4 + wave;

    const int p = ptr_ids[t];
    int idx[3];
#pragma unroll
    for (int w = 0; w < 3; w++) {
        int v = p + w;
        idx[w] = v < (LL - 1) ? v : (LL - 1);
        if (idx[w] < 0) idx[w] = 0;
    }
    const int rel = adv_ids[idx[0]];

    const unsigned short* qrow = Q + (size_t)t * 2048 + lane * 16;
    us8v qj0 = *reinterpret_cast<const us8v*>(qrow);
    us8v qj1 = *reinterpret_cast<const us8v*>(qrow + 8);
    us8v qi0 = *reinterpret_cast<const us8v*>(qrow + 1024);
    us8v qi1 = *reinterpret_cast<const us8v*>(qrow + 1032);

    float sj[3], si[3];
    us8v vj[3][2], vi[3][2];
#pragma unroll
    for (int w = 0; w < 3; w++) {
        const unsigned short* kvrow = KV + (size_t)idx[w] * 4096 + lane * 16;
        us8v kj0 = *reinterpret_cast<const us8v*>(kvrow);
        us8v kj1 = *reinterpret_cast<const us8v*>(kvrow + 8);
        vj[w][0] = *reinterpret_cast<const us8v*>(kvrow + 1024);
        vj[w][1] = *reinterpret_cast<const us8v*>(kvrow + 1032);
        us8v ki0 = *reinterpret_cast<const us8v*>(kvrow + 2048);
        us8v ki1 = *reinterpret_cast<const us8v*>(kvrow + 2056);
        vi[w][0] = *reinterpret_cast<const us8v*>(kvrow + 3072);
        vi[w][1] = *reinterpret_cast<const us8v*>(kvrow + 3080);

        float dj = 0.f, di = 0.f;
#pragma unroll
        for (int e = 0; e < 8; e++) {
            dj += b2f(qj0[e]) * b2f(kj0[e]);
            dj += b2f(qj1[e]) * b2f(kj1[e]);
            di += b2f(qi0[e]) * b2f(ki0[e]);
            di += b2f(qi1[e]) * b2f(ki1[e]);
        }
        sj[w] = wave_sum(dj) * 0.03125f;
        si[w] = wave_sum(di) * 0.03125f;
    }

    const float l1 = sj[1], l2 = sj[2];
    float lf;
    switch (rel) {
        case 0: lf = l1 + l2; break;
        case 1: lf = fmaxf(l1, l2); break;
        case 2: lf = -l1; break;
        case 3: lf = fmaxf(-l1, l2); break;
        case 4: lf = fabsf(l1 - l2); break;
        default: lf = sj[0]; break;
    }

    float mj = fmaxf(lf, fmaxf(l1, l2));
    float ej0 = expf(lf - mj), ej1 = expf(l1 - mj), ej2 = expf(l2 - mj);
    float invj = 1.0f / (ej0 + ej1 + ej2);
    float aj0 = ej0 * invj, aj1 = ej1 * invj, aj2 = ej2 * invj;

    float mi2 = fmaxf(si[0], fmaxf(si[1], si[2]));
    float ei0 = expf(si[0] - mi2), ei1 = expf(si[1] - mi2), ei2 = expf(si[2] - mi2);
    float invi = 1.0f / (ei0 + ei1 + ei2);
    float ai0 = ei0 * invi, ai1 = ei1 * invi, ai2 = ei2 * invi;

    float c0 = council[0], c1 = council[1];
    float cm = fmaxf(c0, c1);
    float w0 = expf(c0 - cm), w1 = expf(c1 - cm);
    float wsum = 1.0f / (w0 + w1);
    w0 *= wsum; w1 *= wsum;
    const float g = *gain_p;

    float* dst = out + (size_t)t * 1024 + lane * 16;
#pragma unroll
    for (int h = 0; h < 2; h++) {
        float4 o0, o1;
        float* op[2] = {&o0.x, &o1.x};
#pragma unroll
        for (int e = 0; e < 8; e++) {
            float cj = aj0 * b2f(vj[0][h][e]) + aj1 * b2f(vj[1][h][e]) + aj2 * b2f(vj[2][h][e]);
            float ci = ai0 * b2f(vi[0][h][e]) + ai1 * b2f(vi[1][h][e]) + ai2 * b2f(vi[2][h][e]);
            op[e >> 2][e & 3] = (w0 * cj + w1 * ci) * g;
        }
        reinterpret_cast<float4*>(dst + h * 8)[0] = o0;
        reinterpret_cast<float4*>(dst + h * 8)[1] = o1;
    }
}

// ---------------- launch ----------------
extern "C" void kernel_launch(void* const* d_in, const int* in_sizes, int n_in,
                              void* d_out, int out_size, void* d_ws, size_t ws_size,
                              hipStream_t stream) {
    const float* hs      = (const float*)d_in[0];
    const float* adv     = (const float*)d_in[1];
    const int*   adv_ids = (const int*)d_in[2];
    const int*   ptr_ids = (const int*)d_in[3];
    const float* Wqj = (const float*)d_in[4];
    const float* Wkj = (const float*)d_in[5];
    const float* Wvj = (const float*)d_in[6];
    const float* Wqi = (const float*)d_in[7];
    const float* Wki = (const float*)d_in[8];
    const float* Wvi = (const float*)d_in[9];
    const float* Wout = (const float*)d_in[10];
    const float* gain = (const float*)d_in[11];
    const float* council = (const float*)d_in[12];
    float* out = (float*)d_out;

    const size_t WN  = (size_t)HH * HH;
    const size_t NHb = (size_t)TT * HH;
    dim3 blk(256);

    auto cvt = [&](const float* s, unsigned short* d, size_t n) {
        int n4 = (int)(n / 4);
        cvt_f32_bf16_k<<<dim3(n4 / 256), blk, 0, stream>>>((const float4*)s, (ushort4*)d, n4);
    };

    // ---- weight buffers: 18 MB ----
    char* ws = (char*)d_ws;
    unsigned short* Wq    = (unsigned short*)ws;  ws += WN * 2 * 2;   // [2048][1024]
    unsigned short* Wkv   = (unsigned short*)ws;  ws += WN * 4 * 2;   // [kj|vj2|ki|vi2][1024]
    unsigned short* WoutB = (unsigned short*)ws;  ws += WN * 2;
    unsigned short* WvT   = (unsigned short*)ws;  ws += WN * 2 * 2;   // [WvjT | WviT]

    cvt(Wqj, Wq, WN);
    cvt(Wqi, Wq + WN, WN);
    cvt(Wkj, Wkv, WN);
    cvt(Wki, Wkv + 2 * WN, WN);
    cvt(Wout, WoutB, WN);
    transp_cvt_k<<<dim3(32, 32), blk, 0, stream>>>(Wvj, WvT);
    transp_cvt_k<<<dim3(32, 32), blk, 0, stream>>>(Wvi, WvT + WN);
    gemm_fold<<<dim3(16, 8), blk, 0, stream>>>(WoutB, WvT, Wkv + WN, Wkv + 3 * WN);

    const size_t full_need = (size_t)(18 * 1024 * 1024) + (NHb * BB) * 2
                           + (size_t)16384 * 2048 * 2 + (size_t)16384 * 4096 * 2;

    if (ws_size >= full_need) {
        unsigned short* advb = (unsigned short*)ws;  ws += NHb * BB * 2;
        unsigned short* Qb   = (unsigned short*)ws;  ws += (size_t)16384 * 2048 * 2;
        unsigned short* KVb  = (unsigned short*)ws;
        unsigned short* hsb  = KVb;                   // aliased; consumed before KVb written

        cvt(hs, hsb, NHb * BB);
        cvt(adv, advb, NHb * BB);
        gemm256<<<dim3(8 * 64), dim3(512), 0, stream>>>(hsb, Wq, Qb, 16384, 2048, 1024, 8);
        gemm256<<<dim3(16 * 64), dim3(512), 0, stream>>>(advb, Wkv, KVb, 16384, 4096, 1024, 16);
        for (int b = 0; b < BB; b++)
            attn_k<<<dim3(TT / 4), blk, 0, stream>>>(Qb + (size_t)b * TT * 2048,
                                                     KVb + (size_t)b * LL * 4096,
                                                     adv_ids + b * LL, ptr_ids + b * TT,
                                                     council, gain, out + (size_t)b * NHb);
    } else {
        unsigned short* advb = (unsigned short*)ws;  ws += NHb * 2;
        unsigned short* Qb   = (unsigned short*)ws;  ws += (size_t)TT * 2048 * 2;
        unsigned short* KVb  = (unsigned short*)ws;
        unsigned short* hsb  = KVb;                   // aliased

        for (int b = 0; b < BB; b++) {
            cvt(hs + (size_t)b * NHb, hsb, NHb);
            cvt(adv + (size_t)b * NHb, advb, NHb);
            gemm256<<<dim3(8 * 16), dim3(512), 0, stream>>>(hsb, Wq, Qb, TT, 2048, 1024, 8);
            gemm256<<<dim3(16 * 16), dim3(512), 0, stream>>>(advb, Wkv, KVb, LL, 4096, 1024, 16);
            attn_k<<<dim3(TT / 4), blk, 0, stream>>>(Qb, KVb, adv_ids + b * LL,
                                                     ptr_ids + b * TT, council, gain,
                                                     out + (size_t)b * NHb);
        }
    }
}

// Round 7
// 372.687 us; speedup vs baseline: 1.0135x; 1.0135x over previous
//
#include <hip/hip_runtime.h>
#include <hip/hip_bf16.h>
#include <stdint.h>

// Problem constants: B=4, T=4096, L=4096, H=1024
#define BB 4
#define TT 4096
#define LL 4096
#define HH 1024

typedef __bf16 bf16x8 __attribute__((ext_vector_type(8)));
typedef float f32x4 __attribute__((ext_vector_type(4)));
typedef float f32x16 __attribute__((ext_vector_type(16)));
typedef unsigned short us8v __attribute__((ext_vector_type(8)));
typedef unsigned short us;

__device__ __forceinline__ unsigned short f2b(float f) {
    unsigned u = __builtin_bit_cast(unsigned, f);
    unsigned r = (u + 0x7FFFu + ((u >> 16) & 1u)) >> 16;
    return (unsigned short)r;
}
__device__ __forceinline__ float b2f(unsigned short u) {
    unsigned x = ((unsigned)u) << 16;
    return __builtin_bit_cast(float, x);
}

__device__ __forceinline__ void gload_lds16(const void* g, void* l) {
    __builtin_amdgcn_global_load_lds(
        (const __attribute__((address_space(1))) void*)(uintptr_t)g,
        (__attribute__((address_space(3))) void*)(uintptr_t)l,
        16, 0, 0);
}

// ---------------- f32 -> bf16 conversion (big tensors) ----------------
__global__ __launch_bounds__(256) void cvt_f32_bf16_k(const float4* __restrict__ src,
                                                      ushort4* __restrict__ dst, int n4) {
    int i = blockIdx.x * 256 + threadIdx.x;
    if (i >= n4) return;
    float4 v = src[i];
    ushort4 o;
    o.x = f2b(v.x); o.y = f2b(v.y); o.z = f2b(v.z); o.w = f2b(v.w);
    dst[i] = o;
}

// ---------------- 5 weight converts in one launch ----------------
struct CvtArgs { const float* s[5]; unsigned short* d[5]; };
__global__ __launch_bounds__(256) void cvt5_k(CvtArgs a) {
    const int g = blockIdx.y;
    const float4* src = (const float4*)a.s[g];
    ushort4* dst = (ushort4*)a.d[g];
    int i = blockIdx.x * 256 + threadIdx.x;   // 1024 blocks x 256 = 262144 = WN/4 exact
    float4 v = src[i];
    ushort4 o;
    o.x = f2b(v.x); o.y = f2b(v.y); o.z = f2b(v.z); o.w = f2b(v.w);
    dst[i] = o;
}

// ---------------- two f32 [1024][1024] -> bf16 transposes in one launch --------------
__global__ __launch_bounds__(256) void transp2_cvt_k(const float* __restrict__ s0,
                                                     unsigned short* __restrict__ d0,
                                                     const float* __restrict__ s1,
                                                     unsigned short* __restrict__ d1) {
    __shared__ float tile[32][33];
    const float* src = blockIdx.z ? s1 : s0;
    unsigned short* dst = blockIdx.z ? d1 : d0;
    const int lx = threadIdx.x & 31, ly = threadIdx.x >> 5;
    const int R = blockIdx.y * 32, C = blockIdx.x * 32;
#pragma unroll
    for (int rr = 0; rr < 4; rr++)
        tile[ly + rr * 8][lx] = src[(size_t)(R + ly + rr * 8) * HH + C + lx];
    __syncthreads();
#pragma unroll
    for (int rr = 0; rr < 4; rr++)
        dst[(size_t)(C + ly + rr * 8) * HH + R + lx] = f2b(tile[lx][ly + rr * 8]);
}

// ---------------- fold GEMM (128x128, 16x16x32, verified) ----------------------------
__global__ __launch_bounds__(256) void gemm_fold(const unsigned short* __restrict__ A,
                                                 const unsigned short* __restrict__ Bw,
                                                 unsigned short* __restrict__ dst1,
                                                 unsigned short* __restrict__ dst2) {
    const int K = 1024;
    __shared__ unsigned short ldsA[128 * 64];
    __shared__ unsigned short ldsB[128 * 64];

    const int tid = threadIdx.x;
    const int wave = tid >> 6, lane = tid & 63;
    const int m0 = blockIdx.y * 128, n0 = blockIdx.x * 128;
    const int wr = wave >> 1, wc = wave & 1;

    f32x4 acc[4][4];
#pragma unroll
    for (int m = 0; m < 4; m++)
#pragma unroll
        for (int n = 0; n < 4; n++) acc[m][n] = (f32x4)(0.0f);

    const unsigned short* Ab = A + (size_t)m0 * K;
    const unsigned short* Bb = Bw + (size_t)n0 * K;
    const int rbase = tid >> 3;
    const int col0 = (((tid & 7) ^ (rbase & 7)) << 3);

    for (int k0 = 0; k0 < K; k0 += 64) {
#pragma unroll
        for (int r = 0; r < 4; r++) {
            const int row = r * 32 + rbase;
            gload_lds16(Ab + (size_t)row * K + k0 + col0, &ldsA[r * 2048 + wave * 512]);
            gload_lds16(Bb + (size_t)row * K + k0 + col0, &ldsB[r * 2048 + wave * 512]);
        }
        __syncthreads();

        const int lr = lane & 15, hi = lane >> 4;
        const int sw = (lr & 7) << 4;
        const int c0 = ((hi * 16) ^ sw) >> 1;
        const int c1 = ((64 + hi * 16) ^ sw) >> 1;
        bf16x8 a0[4], a1[4], b0[4], b1[4];
#pragma unroll
        for (int m = 0; m < 4; m++) {
            const int row = (wr * 64 + m * 16 + lr) * 64;
            a0[m] = *reinterpret_cast<const bf16x8*>(&ldsA[row + c0]);
            a1[m] = *reinterpret_cast<const bf16x8*>(&ldsA[row + c1]);
        }
#pragma unroll
        for (int n = 0; n < 4; n++) {
            const int row = (wc * 64 + n * 16 + lr) * 64;
            b0[n] = *reinterpret_cast<const bf16x8*>(&ldsB[row + c0]);
            b1[n] = *reinterpret_cast<const bf16x8*>(&ldsB[row + c1]);
        }
#pragma unroll
        for (int m = 0; m < 4; m++)
#pragma unroll
            for (int n = 0; n < 4; n++)
                acc[m][n] = __builtin_amdgcn_mfma_f32_16x16x32_bf16(a0[m], b0[n], acc[m][n], 0, 0, 0);
#pragma unroll
        for (int m = 0; m < 4; m++)
#pragma unroll
            for (int n = 0; n < 4; n++)
                acc[m][n] = __builtin_amdgcn_mfma_f32_16x16x32_bf16(a1[m], b1[n], acc[m][n], 0, 0, 0);
        __syncthreads();
    }

    const int cc = lane & 15, cr = (lane >> 4) * 4;
#pragma unroll
    for (int m = 0; m < 4; m++)
#pragma unroll
        for (int n = 0; n < 4; n++)
#pragma unroll
            for (int r = 0; r < 4; r++) {
                const int row = m0 + wr * 64 + m * 16 + cr + r;
                const int col = n0 + wc * 64 + n * 16 + cc;
                unsigned short* base = (col < 1024) ? dst1 : dst2;
                base[(size_t)row * 1024 + (col & 1023)] = f2b(acc[m][n][r]);
            }
}

// ---------------- 256x256 GEMM, R5 schedule + 32x32x16 MFMA --------------------------
// 8 waves (2M x 4N), per-wave 128x64 = 4mi(32r) x 2ni(32c) frags. BK=64 as two
// kk-chunks of 32; chunk [256 rows][32 k] stored as 2-row/128B units, 8-slot XOR
// swizzle (slot ^= unit&7). Double-buffered (128 KiB). Counted vmcnt(4); single
// barrier per half; compiler-scheduled lgkmcnt for ds_read->MFMA.
#define BAR __builtin_amdgcn_s_barrier()
#define SB0 __builtin_amdgcn_sched_barrier(0)
#define VMW4 asm volatile("s_waitcnt vmcnt(4)" ::: "memory")
#define VMW0 asm volatile("s_waitcnt vmcnt(0)" ::: "memory")
#define NOWAIT

#define STAGE2(chunk, src, kcol) \
    { _Pragma("unroll") for (int r_ = 0; r_ < 2; r_++) \
        gload_lds16((src) + (size_t)srow[r_] * K + (kcol) + scol[r_], (chunk) + r_ * 4096 + wave * 512); }

#define RDAB(cE) { \
    _Pragma("unroll") for (int m_ = 0; m_ < 4; m_++) \
    _Pragma("unroll") for (int k_ = 0; k_ < 2; k_++) \
        a[m_][k_] = *reinterpret_cast<const bf16x8*>((cE) + offA[k_] + m_ * 1024); \
    _Pragma("unroll") for (int n_ = 0; n_ < 2; n_++) \
    _Pragma("unroll") for (int k_ = 0; k_ < 2; k_++) \
        b[n_][k_] = *reinterpret_cast<const bf16x8*>((cE) + 16384 + offB[k_] + n_ * 1024); }

#define MFMA16 { __builtin_amdgcn_s_setprio(1); \
    _Pragma("unroll") for (int m_ = 0; m_ < 4; m_++) \
    _Pragma("unroll") for (int n_ = 0; n_ < 2; n_++) { \
        acc[m_][n_] = __builtin_amdgcn_mfma_f32_32x32x16_bf16(a[m_][0], b[n_][0], acc[m_][n_], 0, 0, 0); \
        acc[m_][n_] = __builtin_amdgcn_mfma_f32_32x32x16_bf16(a[m_][1], b[n_][1], acc[m_][n_], 0, 0, 0); } \
    __builtin_amdgcn_s_setprio(0); }

// One half-K-tile (one kk-chunk pair of A+B): read 12 frags, stage next chunks,
// 16 MFMA (32x32x16), counted wait, barrier pin.
#define HALF(cE, nA, nB, kn, STG, WAIT)                          \
  {                                                               \
    RDAB(cE);                                                     \
    if (STG) { STAGE2(nA, Ablk, (kn)); STAGE2(nB, Bblk, (kn)); }  \
    MFMA16;                                                       \
    WAIT;                                                         \
    BAR; SB0;                                                     \
  }

__global__ __launch_bounds__(512, 2) void gemm256(const us* __restrict__ A,
                                                  const us* __restrict__ Bw,
                                                  us* __restrict__ C,
                                                  int M, int N, int K, int gx) {
    __shared__ us lds[65536];   // 128 KB: {A-kk0, A-kk1, B-kk0, B-kk1} x2 buffers

    const int nwg = gridDim.x;
    const int bid = blockIdx.x;
    const int swz = (bid & 7) * (nwg >> 3) + (bid >> 3);   // grids multiple of 8
    const int bx = swz % gx, by = swz / gx;
    const int m0 = by * 256, n0 = bx * 256;

    const int tid = threadIdx.x;
    const int wave = tid >> 6, lane = tid & 63;
    const int wr = wave >> 2, wc = wave & 3;
    const int l31 = lane & 31, koct = lane >> 5;

    // stage source mapping (inverse swizzle): chunk byte = r_*8192 + tid*16
    int srow[2], scol[2];
#pragma unroll
    for (int r = 0; r < 2; r++) {
        const int q = r * 64 + (tid >> 3);
        const int s = (tid & 7) ^ (q & 7);
        srow[r] = 2 * q + (s >> 2);
        scol[r] = (s & 3) * 8;
    }
    const us* Ablk = A + (size_t)m0 * K;
    const us* Bblk = Bw + (size_t)n0 * K;

    // ds_read offsets (elems within a chunk) for 32x32x16 frags:
    // A: row = wr*128 + mi*32 + l31, k0 = kksub*16 + koct*8
    // off = (row>>1)*64 + (((row&1)<<2 | (k0>>3)) ^ ((row>>1)&7)) << 3 ; mi step = +1024
    int offA[2], offB[2];
    {
        const int rA = wr * 128 + l31, uA = rA >> 1, pA = (rA & 1) << 2;
        const int rB = wc * 64 + l31,  uB = rB >> 1, pB = (rB & 1) << 2;
#pragma unroll
        for (int k = 0; k < 2; k++) {
            offA[k] = uA * 64 + (((pA | (k * 2 + koct)) ^ (uA & 7)) << 3);
            offB[k] = uB * 64 + (((pB | (k * 2 + koct)) ^ (uB & 7)) << 3);
        }
    }

    f32x16 acc[4][2];
#pragma unroll
    for (int m = 0; m < 4; m++)
#pragma unroll
        for (int n = 0; n < 2; n++) acc[m][n] = (f32x16)(0.0f);

    us* c0 = lds;            // buffer0: A0 | A1 | B0 | B1 (8192 elems each)
    us* c1 = lds + 32768;    // buffer1
    bf16x8 a[4][2], b[2][2];

    // prologue: stage tile 0 (A-kk0, B-kk0, A-kk1, B-kk1)
    STAGE2(c0,          Ablk, 0);
    STAGE2(c0 + 16384,  Bblk, 0);
    STAGE2(c0 + 8192,   Ablk, 32);
    STAGE2(c0 + 24576,  Bblk, 32);
    VMW4;            // drains kk0 pair
    BAR; SB0;

    const int NT = K >> 6;
    for (int t = 0; t < NT - 1; ++t) {
        const int kn = (t + 1) << 6;
        us* cur = (t & 1) ? c1 : c0;
        us* nxt = (t & 1) ? c0 : c1;
        // half 0 (kk0): VMW4 drains prev tile's kk1 pair (this tile's kk1 = next read)
        HALF(cur, nxt, nxt + 16384, kn, true, VMW4);
        // half 1 (kk1): VMW4 drains next tile's kk0 pair
        HALF(cur + 8192, nxt + 8192, nxt + 24576, kn + 32, true, VMW4);
    }
    {
        us* cur = ((NT - 1) & 1) ? c1 : c0;
        HALF(cur, cur, cur, 0, false, VMW0);
        HALF(cur + 8192, cur, cur, 0, false, NOWAIT);
    }

    // C write (32x32 frag layout, m74/m101): col = lane&31, row = (reg&3)+8*(reg>>2)+4*koct
    const int crow = m0 + wr * 128 + 4 * koct;
    const int ccol = n0 + wc * 64 + l31;
#pragma unroll
    for (int mi = 0; mi < 4; mi++)
#pragma unroll
        for (int ni = 0; ni < 2; ni++)
#pragma unroll
            for (int rr = 0; rr < 16; rr++) {
                const int row = crow + mi * 32 + (rr & 3) + 8 * (rr >> 2);
                C[(size_t)row * N + ccol + ni * 32] = f2b(acc[mi][ni][rr]);
            }
}

// ---------------- windowed 3-way gated attention (all batches, fused output) ----------
__device__ __forceinline__ float wave_sum(float v) {
#pragma unroll
    for (int off = 32; off > 0; off >>= 1) v += __shfl_xor(v, off, 64);
    return v;
}

__global__ __launch_bounds__(256) void attn_k(const unsigned short* __restrict__ Q,
                                              const unsigned short* __restrict__ KV,
                                              const int* __restrict__ adv_ids,
                                              const int* __restrict__ ptr_ids,
                                              const float* __restrict__ council,
                                              const float* __restrict__ gain_p,
                                              float* __restrict__ out) {
    const int wave = threadIdx.x >> 6, lane = threadIdx.x & 63;
    const int gid = blockIdx.x * 4 + wave;   // [0, nbat*T)
    const int b = gid >> 12, t = gid & 4095;

    const int p = ptr_ids[b * TT + t];
    int idx[3];
#pragma unroll
    for (int w = 0; w < 3; w++) {
        int v = p + w;
        idx[w] = v < (LL - 1) ? v : (LL - 1);
        if (idx[w] < 0) idx[w] = 0;
    }
    const int rel = adv_ids[b * LL + idx[0]];

    const unsigned short* qrow = Q + (size_t)gid * 2048 + lane * 16;
    us8v qj0 = *reinterpret_cast<const us8v*>(qrow);
    us8v qj1 = *reinterpret_cast<const us8v*>(qrow + 8);
    us8v qi0 = *reinterpret_cast<const us8v*>(qrow + 1024);
    us8v qi1 = *reinterpret_cast<const us8v*>(qrow + 1032);

    float sj[3], si[3];
    us8v vj[3][2], vi[3][2];
#pragma unroll
    for (int w = 0; w < 3; w++) {
        const unsigned short* kvrow = KV + (size_t)(b * LL + idx[w]) * 4096 + lane * 16;
        us8v kj0 = *reinterpret_cast<const us8v*>(kvrow);
        us8v kj1 = *reinterpret_cast<const us8v*>(kvrow + 8);
        vj[w][0] = *reinterpret_cast<const us8v*>(kvrow + 1024);
        vj[w][1] = *reinterpret_cast<const us8v*>(kvrow + 1032);
        us8v ki0 = *reinterpret_cast<const us8v*>(kvrow + 2048);
        us8v ki1 = *reinterpret_cast<const us8v*>(kvrow + 2056);
        vi[w][0] = *reinterpret_cast<const us8v*>(kvrow + 3072);
        vi[w][1] = *reinterpret_cast<const us8v*>(kvrow + 3080);

        float dj = 0.f, di = 0.f;
#pragma unroll
        for (int e = 0; e < 8; e++) {
            dj += b2f(qj0[e]) * b2f(kj0[e]);
            dj += b2f(qj1[e]) * b2f(kj1[e]);
            di += b2f(qi0[e]) * b2f(ki0[e]);
            di += b2f(qi1[e]) * b2f(ki1[e]);
        }
        sj[w] = wave_sum(dj) * 0.03125f;
        si[w] = wave_sum(di) * 0.03125f;
    }

    const float l1 = sj[1], l2 = sj[2];
    float lf;
    switch (rel) {
        case 0: lf = l1 + l2; break;
        case 1: lf = fmaxf(l1, l2); break;
        case 2: lf = -l1; break;
        case 3: lf = fmaxf(-l1, l2); break;
        case 4: lf = fabsf(l1 - l2); break;
        default: lf = sj[0]; break;
    }

    float mj = fmaxf(lf, fmaxf(l1, l2));
    float ej0 = expf(lf - mj), ej1 = expf(l1 - mj), ej2 = expf(l2 - mj);
    float invj = 1.0f / (ej0 + ej1 + ej2);
    float aj0 = ej0 * invj, aj1 = ej1 * invj, aj2 = ej2 * invj;

    float mi2 = fmaxf(si[0], fmaxf(si[1], si[2]));
    float ei0 = expf(si[0] - mi2), ei1 = expf(si[1] - mi2), ei2 = expf(si[2] - mi2);
    float invi = 1.0f / (ei0 + ei1 + ei2);
    float ai0 = ei0 * invi, ai1 = ei1 * invi, ai2 = ei2 * invi;

    float c0 = council[0], c1 = council[1];
    float cm = fmaxf(c0, c1);
    float w0 = expf(c0 - cm), w1 = expf(c1 - cm);
    float wsum = 1.0f / (w0 + w1);
    w0 *= wsum; w1 *= wsum;
    const float g = *gain_p;

    float* dst = out + (size_t)gid * 1024 + lane * 16;
#pragma unroll
    for (int h = 0; h < 2; h++) {
        float4 o0, o1;
        float* op[2] = {&o0.x, &o1.x};
#pragma unroll
        for (int e = 0; e < 8; e++) {
            float cj = aj0 * b2f(vj[0][h][e]) + aj1 * b2f(vj[1][h][e]) + aj2 * b2f(vj[2][h][e]);
            float ci = ai0 * b2f(vi[0][h][e]) + ai1 * b2f(vi[1][h][e]) + ai2 * b2f(vi[2][h][e]);
            op[e >> 2][e & 3] = (w0 * cj + w1 * ci) * g;
        }
        reinterpret_cast<float4*>(dst + h * 8)[0] = o0;
        reinterpret_cast<float4*>(dst + h * 8)[1] = o1;
    }
}

// ---------------- launch ----------------
extern "C" void kernel_launch(void* const* d_in, const int* in_sizes, int n_in,
                              void* d_out, int out_size, void* d_ws, size_t ws_size,
                              hipStream_t stream) {
    const float* hs      = (const float*)d_in[0];
    const float* adv     = (const float*)d_in[1];
    const int*   adv_ids = (const int*)d_in[2];
    const int*   ptr_ids = (const int*)d_in[3];
    const float* Wqj = (const float*)d_in[4];
    const float* Wkj = (const float*)d_in[5];
    const float* Wvj = (const float*)d_in[6];
    const float* Wqi = (const float*)d_in[7];
    const float* Wki = (const float*)d_in[8];
    const float* Wvi = (const float*)d_in[9];
    const float* Wout = (const float*)d_in[10];
    const float* gain = (const float*)d_in[11];
    const float* council = (const float*)d_in[12];
    float* out = (float*)d_out;

    const size_t WN  = (size_t)HH * HH;
    const size_t NHb = (size_t)TT * HH;
    dim3 blk(256);

    auto cvt = [&](const float* s, unsigned short* d, size_t n) {
        int n4 = (int)(n / 4);
        cvt_f32_bf16_k<<<dim3(n4 / 256), blk, 0, stream>>>((const float4*)s, (ushort4*)d, n4);
    };

    // ---- weight buffers: 18 MB ----
    char* ws = (char*)d_ws;
    unsigned short* Wq    = (unsigned short*)ws;  ws += WN * 2 * 2;   // [2048][1024]
    unsigned short* Wkv   = (unsigned short*)ws;  ws += WN * 4 * 2;   // [kj|vj2|ki|vi2][1024]
    unsigned short* WoutB = (unsigned short*)ws;  ws += WN * 2;
    unsigned short* WvT   = (unsigned short*)ws;  ws += WN * 2 * 2;   // [WvjT | WviT]

    CvtArgs ca;
    ca.s[0] = Wqj;  ca.d[0] = Wq;
    ca.s[1] = Wqi;  ca.d[1] = Wq + WN;
    ca.s[2] = Wkj;  ca.d[2] = Wkv;
    ca.s[3] = Wki;  ca.d[3] = Wkv + 2 * WN;
    ca.s[4] = Wout; ca.d[4] = WoutB;
    cvt5_k<<<dim3(1024, 5), blk, 0, stream>>>(ca);
    transp2_cvt_k<<<dim3(32, 32, 2), blk, 0, stream>>>(Wvj, WvT, Wvi, WvT + WN);
    gemm_fold<<<dim3(16, 8), blk, 0, stream>>>(WoutB, WvT, Wkv + WN, Wkv + 3 * WN);

    const size_t full_need = (size_t)(18 * 1024 * 1024) + (NHb * BB) * 2
                           + (size_t)16384 * 2048 * 2 + (size_t)16384 * 4096 * 2;

    if (ws_size >= full_need) {
        unsigned short* advb = (unsigned short*)ws;  ws += NHb * BB * 2;
        unsigned short* Qb   = (unsigned short*)ws;  ws += (size_t)16384 * 2048 * 2;
        unsigned short* KVb  = (unsigned short*)ws;
        unsigned short* hsb  = KVb;                   // aliased; consumed before KVb written

        cvt(hs, hsb, NHb * BB);
        cvt(adv, advb, NHb * BB);
        gemm256<<<dim3(8 * 64), dim3(512), 0, stream>>>(hsb, Wq, Qb, 16384, 2048, 1024, 8);
        gemm256<<<dim3(16 * 64), dim3(512), 0, stream>>>(advb, Wkv, KVb, 16384, 4096, 1024, 16);
        attn_k<<<dim3((BB * TT) / 4), blk, 0, stream>>>(Qb, KVb, adv_ids, ptr_ids,
                                                        council, gain, out);
    } else {
        unsigned short* advb = (unsigned short*)ws;  ws += NHb * 2;
        unsigned short* Qb   = (unsigned short*)ws;  ws += (size_t)TT * 2048 * 2;
        unsigned short* KVb  = (unsigned short*)ws;
        unsigned short* hsb  = KVb;                   // aliased

        for (int b = 0; b < BB; b++) {
            cvt(hs + (size_t)b * NHb, hsb, NHb);
            cvt(adv + (size_t)b * NHb, advb, NHb);
            gemm256<<<dim3(8 * 16), dim3(512), 0, stream>>>(hsb, Wq, Qb, TT, 2048, 1024, 8);
            gemm256<<<dim3(16 * 16), dim3(512), 0, stream>>>(advb, Wkv, KVb, LL, 4096, 1024, 16);
            attn_k<<<dim3(TT / 4), blk, 0, stream>>>(Qb, KVb, adv_ids + b * LL,
                                                     ptr_ids + b * TT, council, gain,
                                                     out + (size_t)b * NHb);
        }
    }
}

// Round 8
// 268.243 us; speedup vs baseline: 1.4082x; 1.3894x over previous
//
#include <hip/hip_runtime.h>
#include <hip/hip_bf16.h>
#include <stdint.h>

// Problem constants: B=4, T=4096, L=4096, H=1024
#define BB 4
#define TT 4096
#define LL 4096
#define HH 1024

typedef __bf16 bf16x8 __attribute__((ext_vector_type(8)));
typedef float f32x4 __attribute__((ext_vector_type(4)));
typedef unsigned short us8v __attribute__((ext_vector_type(8)));
typedef unsigned short us;

__device__ __forceinline__ unsigned short f2b(float f) {
    unsigned u = __builtin_bit_cast(unsigned, f);
    unsigned r = (u + 0x7FFFu + ((u >> 16) & 1u)) >> 16;
    return (unsigned short)r;
}
__device__ __forceinline__ float b2f(unsigned short u) {
    unsigned x = ((unsigned)u) << 16;
    return __builtin_bit_cast(float, x);
}

__device__ __forceinline__ void gload_lds16(const void* g, void* l) {
    __builtin_amdgcn_global_load_lds(
        (const __attribute__((address_space(1))) void*)(uintptr_t)g,
        (__attribute__((address_space(3))) void*)(uintptr_t)l,
        16, 0, 0);
}

// ---------------- f32 -> bf16 conversion ----------------
__global__ __launch_bounds__(256) void cvt_f32_bf16_k(const float4* __restrict__ src,
                                                      ushort4* __restrict__ dst, int n4) {
    int i = blockIdx.x * 256 + threadIdx.x;
    if (i >= n4) return;
    float4 v = src[i];
    ushort4 o;
    o.x = f2b(v.x); o.y = f2b(v.y); o.z = f2b(v.z); o.w = f2b(v.w);
    dst[i] = o;
}

// ---------------- six f32 [1024][1024] -> bf16 transposes, one launch ----------------
struct TrArgs { const float* s[6]; unsigned short* d[6]; };
__global__ __launch_bounds__(256) void transp6_cvt_k(TrArgs ta) {
    __shared__ float tile[32][33];
    const int z = blockIdx.z;
    const float* src = ta.s[z];
    unsigned short* dst = ta.d[z];
    const int lx = threadIdx.x & 31, ly = threadIdx.x >> 5;
    const int R = blockIdx.y * 32, C = blockIdx.x * 32;
#pragma unroll
    for (int rr = 0; rr < 4; rr++)
        tile[ly + rr * 8][lx] = src[(size_t)(R + ly + rr * 8) * HH + C + lx];
    __syncthreads();
#pragma unroll
    for (int rr = 0; rr < 4; rr++)
        dst[(size_t)(C + ly + rr * 8) * HH + R + lx] = f2b(tile[lx][ly + rr * 8]);
}

// ---------------- four 1024^3 weight-fold GEMMs in one launch ------------------------
// C_z = A_z @ B_z^T (bf16 in/out, f32 accum), 128x128 tiles, verified 16x16x32 body.
struct FoldArgs { const us* A[4]; const us* B[4]; us* D[4]; };
__global__ __launch_bounds__(256) void gemm_fold4(FoldArgs fa) {
    const int K = 1024;
    __shared__ unsigned short ldsA[128 * 64];
    __shared__ unsigned short ldsB[128 * 64];

    const int z = blockIdx.z;
    const us* A = fa.A[z];
    const us* Bw = fa.B[z];
    us* dst = fa.D[z];

    const int tid = threadIdx.x;
    const int wave = tid >> 6, lane = tid & 63;
    const int m0 = blockIdx.y * 128, n0 = blockIdx.x * 128;
    const int wr = wave >> 1, wc = wave & 1;

    f32x4 acc[4][4];
#pragma unroll
    for (int m = 0; m < 4; m++)
#pragma unroll
        for (int n = 0; n < 4; n++) acc[m][n] = (f32x4)(0.0f);

    const us* Ab = A + (size_t)m0 * K;
    const us* Bb = Bw + (size_t)n0 * K;
    const int rbase = tid >> 3;
    const int col0 = (((tid & 7) ^ (rbase & 7)) << 3);

    for (int k0 = 0; k0 < K; k0 += 64) {
#pragma unroll
        for (int r = 0; r < 4; r++) {
            const int row = r * 32 + rbase;
            gload_lds16(Ab + (size_t)row * K + k0 + col0, &ldsA[r * 2048 + wave * 512]);
            gload_lds16(Bb + (size_t)row * K + k0 + col0, &ldsB[r * 2048 + wave * 512]);
        }
        __syncthreads();

        const int lr = lane & 15, hi = lane >> 4;
        const int sw = (lr & 7) << 4;
        const int c0 = ((hi * 16) ^ sw) >> 1;
        const int c1 = ((64 + hi * 16) ^ sw) >> 1;
        bf16x8 a0[4], a1[4], b0[4], b1[4];
#pragma unroll
        for (int m = 0; m < 4; m++) {
            const int row = (wr * 64 + m * 16 + lr) * 64;
            a0[m] = *reinterpret_cast<const bf16x8*>(&ldsA[row + c0]);
            a1[m] = *reinterpret_cast<const bf16x8*>(&ldsA[row + c1]);
        }
#pragma unroll
        for (int n = 0; n < 4; n++) {
            const int row = (wc * 64 + n * 16 + lr) * 64;
            b0[n] = *reinterpret_cast<const bf16x8*>(&ldsB[row + c0]);
            b1[n] = *reinterpret_cast<const bf16x8*>(&ldsB[row + c1]);
        }
#pragma unroll
        for (int m = 0; m < 4; m++)
#pragma unroll
            for (int n = 0; n < 4; n++)
                acc[m][n] = __builtin_amdgcn_mfma_f32_16x16x32_bf16(a0[m], b0[n], acc[m][n], 0, 0, 0);
#pragma unroll
        for (int m = 0; m < 4; m++)
#pragma unroll
            for (int n = 0; n < 4; n++)
                acc[m][n] = __builtin_amdgcn_mfma_f32_16x16x32_bf16(a1[m], b1[n], acc[m][n], 0, 0, 0);
        __syncthreads();
    }

    const int cc = lane & 15, cr = (lane >> 4) * 4;
#pragma unroll
    for (int m = 0; m < 4; m++)
#pragma unroll
        for (int n = 0; n < 4; n++)
#pragma unroll
            for (int r = 0; r < 4; r++) {
                const int row = m0 + wr * 64 + m * 16 + cr + r;
                const int col = n0 + wc * 64 + n * 16 + cc;
                dst[(size_t)row * 1024 + col] = f2b(acc[m][n][r]);
            }
}

// ---------------- 256x256 GEMM (R5 structure, 16x16x32, 0-conflict swizzle) ----------
// 8 waves (2M x 4N), per-wave 128x64 = 8x4 frags. BK=64 as two kk-chunks of 32;
// chunk [256r][32k] as 2-row/128B units, 8-slot XOR swizzle. Double-buffered 128 KiB.
// Counted vmcnt(4); one barrier per half; compiler-scheduled lgkmcnt for ds_read->MFMA.
__device__ __forceinline__ void mfma32(const bf16x8 a[8], const bf16x8 b[4], f32x4 acc[8][4]) {
    __builtin_amdgcn_s_setprio(1);
#pragma unroll
    for (int m = 0; m < 8; m++)
#pragma unroll
        for (int n = 0; n < 4; n++)
            acc[m][n] = __builtin_amdgcn_mfma_f32_16x16x32_bf16(a[m], b[n], acc[m][n], 0, 0, 0);
    __builtin_amdgcn_s_setprio(0);
}

#define STAGE2(chunk, src, kcol) \
    { _Pragma("unroll") for (int r_ = 0; r_ < 2; r_++) \
        gload_lds16((src) + (size_t)srow[r_] * K + (kcol) + scol[r_], (chunk) + r_ * 4096 + wave * 512); }

#define RD_A8(cA) \
    { _Pragma("unroll") for (int m_ = 0; m_ < 8; m_++) \
        a[m_] = *reinterpret_cast<const bf16x8*>((cA) + offA + m_ * 512); }

#define RD_B4(cB) \
    { _Pragma("unroll") for (int n_ = 0; n_ < 4; n_++) \
        b[n_] = *reinterpret_cast<const bf16x8*>((cB) + offB + n_ * 512); }

#define BAR __builtin_amdgcn_s_barrier()
#define SB0 __builtin_amdgcn_sched_barrier(0)
#define VMW4 asm volatile("s_waitcnt vmcnt(4)" ::: "memory")
#define VMW0 asm volatile("s_waitcnt vmcnt(0)" ::: "memory")
#define NOWAIT

#define HALF(cA, cB, nA, nB, kn, STG, WAIT)                  \
  {                                                           \
    RD_A8(cA); RD_B4(cB);                                     \
    if (STG) { STAGE2(nA, Ablk, (kn)); STAGE2(nB, Bblk, (kn)); } \
    mfma32(a, b, acc);                                        \
    WAIT;                                                     \
    BAR; SB0;                                                 \
  }

__global__ __launch_bounds__(512, 2) void gemm256(const us* __restrict__ A,
                                                  const us* __restrict__ Bw,
                                                  us* __restrict__ C,
                                                  int M, int N, int K, int gx) {
    __shared__ us lds[65536];   // 128 KB

    const int nwg = gridDim.x;
    const int bid = blockIdx.x;
    const int swz = (bid & 7) * (nwg >> 3) + (bid >> 3);   // grids multiple of 8
    const int bx = swz % gx, by = swz / gx;
    const int m0 = by * 256, n0 = bx * 256;

    const int tid = threadIdx.x;
    const int wave = tid >> 6, lane = tid & 63;
    const int wr = wave >> 2, wc = wave & 3;
    const int lr = lane & 15, hi = lane >> 4;

    int srow[2], scol[2];
#pragma unroll
    for (int r = 0; r < 2; r++) {
        const int q = r * 64 + (tid >> 3);
        const int s = (tid & 7) ^ (q & 7);
        srow[r] = 2 * q + (s >> 2);
        scol[r] = (s & 3) * 8;
    }
    const us* Ablk = A + (size_t)m0 * K;
    const us* Bblk = Bw + (size_t)n0 * K;

    const int rA = wr * 128 + lr;
    const int offA = (rA >> 1) * 64 + (((((rA & 1) << 2) + hi) ^ ((rA >> 1) & 7)) << 3);
    const int rB = wc * 64 + lr;
    const int offB = (rB >> 1) * 64 + (((((rB & 1) << 2) + hi) ^ ((rB >> 1) & 7)) << 3);

    f32x4 acc[8][4];
#pragma unroll
    for (int m = 0; m < 8; m++)
#pragma unroll
        for (int n = 0; n < 4; n++) acc[m][n] = (f32x4)(0.0f);

    us* cA0 = lds;          us* cA1 = lds + 8192;
    us* cB0 = lds + 16384;  us* cB1 = lds + 24576;
    us* nA0 = lds + 32768;  us* nA1 = lds + 40960;
    us* nB0 = lds + 49152;  us* nB1 = lds + 57344;

    bf16x8 a[8], b[4];

    STAGE2(cA0, Ablk, 0);
    STAGE2(cB0, Bblk, 0);
    STAGE2(cA1, Ablk, 32);
    STAGE2(cB1, Bblk, 32);
    VMW4;
    BAR; SB0;

    const int NT = K >> 6;
    for (int t = 0; t < NT - 1; ++t) {
        const int kn = (t + 1) << 6;
        HALF(cA0, cB0, nA0, nB0, kn, true, VMW4);
        HALF(cA1, cB1, nA1, nB1, kn + 32, true, VMW4);
        us* s0 = cA0; cA0 = nA0; nA0 = s0;
        us* s1 = cA1; cA1 = nA1; nA1 = s1;
        us* s2 = cB0; cB0 = nB0; nB0 = s2;
        us* s3 = cB1; cB1 = nB1; nB1 = s3;
    }
    HALF(cA0, cB0, nA0, nB0, 0, false, VMW0);
    HALF(cA1, cB1, nA1, nB1, 0, false, NOWAIT);

    const int crow0 = m0 + wr * 128 + hi * 4;
    const int ccol0 = n0 + wc * 64 + lr;
#pragma unroll
    for (int mi = 0; mi < 8; mi++)
#pragma unroll
        for (int ni = 0; ni < 4; ni++)
#pragma unroll
            for (int rr = 0; rr < 4; rr++)
                C[(size_t)(crow0 + mi * 16 + rr) * N + ccol0 + ni * 16] = f2b(acc[mi][ni][rr]);
}

// ---------------- windowed 3-way gated attention, hs-direct (Q GEMM folded away) -----
// HS: [nb*T][1024] f32 (queries = raw hidden states; Wq folded into K' = M @ adv)
// KV: [nb*L][4096] bf16 (kj' | vj' | ki' | vi');  writes final f32 output (x gain).
__device__ __forceinline__ float wave_sum(float v) {
#pragma unroll
    for (int off = 32; off > 0; off >>= 1) v += __shfl_xor(v, off, 64);
    return v;
}

__global__ __launch_bounds__(256) void attn_k(const float* __restrict__ HS,
                                              const unsigned short* __restrict__ KV,
                                              const int* __restrict__ adv_ids,
                                              const int* __restrict__ ptr_ids,
                                              const float* __restrict__ council,
                                              const float* __restrict__ gain_p,
                                              float* __restrict__ out) {
    const int wave = threadIdx.x >> 6, lane = threadIdx.x & 63;
    const int gid = blockIdx.x * 4 + wave;
    const int b = gid >> 12, t = gid & 4095;

    const int p = ptr_ids[b * TT + t];
    int idx[3];
#pragma unroll
    for (int w = 0; w < 3; w++) {
        int v = p + w;
        idx[w] = v < (LL - 1) ? v : (LL - 1);
        if (idx[w] < 0) idx[w] = 0;
    }
    const int rel = adv_ids[b * LL + idx[0]];

    // query = raw hidden state row (f32), 16 channels per lane
    float qf[16];
    {
        const float4* hrow = reinterpret_cast<const float4*>(HS + (size_t)gid * 1024 + lane * 16);
#pragma unroll
        for (int v = 0; v < 4; v++) {
            float4 x = hrow[v];
            qf[v * 4 + 0] = x.x; qf[v * 4 + 1] = x.y; qf[v * 4 + 2] = x.z; qf[v * 4 + 3] = x.w;
        }
    }

    float sj[3], si[3];
    us8v vj[3][2], vi[3][2];
#pragma unroll
    for (int w = 0; w < 3; w++) {
        const unsigned short* kvrow = KV + (size_t)(b * LL + idx[w]) * 4096 + lane * 16;
        us8v kj0 = *reinterpret_cast<const us8v*>(kvrow);
        us8v kj1 = *reinterpret_cast<const us8v*>(kvrow + 8);
        vj[w][0] = *reinterpret_cast<const us8v*>(kvrow + 1024);
        vj[w][1] = *reinterpret_cast<const us8v*>(kvrow + 1032);
        us8v ki0 = *reinterpret_cast<const us8v*>(kvrow + 2048);
        us8v ki1 = *reinterpret_cast<const us8v*>(kvrow + 2056);
        vi[w][0] = *reinterpret_cast<const us8v*>(kvrow + 3072);
        vi[w][1] = *reinterpret_cast<const us8v*>(kvrow + 3080);

        float dj = 0.f, di = 0.f;
#pragma unroll
        for (int e = 0; e < 8; e++) {
            dj += qf[e] * b2f(kj0[e]) + qf[8 + e] * b2f(kj1[e]);
            di += qf[e] * b2f(ki0[e]) + qf[8 + e] * b2f(ki1[e]);
        }
        sj[w] = wave_sum(dj) * 0.03125f;   // 1/sqrt(1024)
        si[w] = wave_sum(di) * 0.03125f;
    }

    const float l1 = sj[1], l2 = sj[2];
    float lf;
    switch (rel) {
        case 0: lf = l1 + l2; break;
        case 1: lf = fmaxf(l1, l2); break;
        case 2: lf = -l1; break;
        case 3: lf = fmaxf(-l1, l2); break;
        case 4: lf = fabsf(l1 - l2); break;
        default: lf = sj[0]; break;
    }

    float mj = fmaxf(lf, fmaxf(l1, l2));
    float ej0 = expf(lf - mj), ej1 = expf(l1 - mj), ej2 = expf(l2 - mj);
    float invj = 1.0f / (ej0 + ej1 + ej2);
    float aj0 = ej0 * invj, aj1 = ej1 * invj, aj2 = ej2 * invj;

    float mi2 = fmaxf(si[0], fmaxf(si[1], si[2]));
    float ei0 = expf(si[0] - mi2), ei1 = expf(si[1] - mi2), ei2 = expf(si[2] - mi2);
    float invi = 1.0f / (ei0 + ei1 + ei2);
    float ai0 = ei0 * invi, ai1 = ei1 * invi, ai2 = ei2 * invi;

    float c0 = council[0], c1 = council[1];
    float cm = fmaxf(c0, c1);
    float w0 = expf(c0 - cm), w1 = expf(c1 - cm);
    float wsum = 1.0f / (w0 + w1);
    w0 *= wsum; w1 *= wsum;
    const float g = *gain_p;

    float* dst = out + (size_t)gid * 1024 + lane * 16;
#pragma unroll
    for (int h = 0; h < 2; h++) {
        float4 o0, o1;
        float* op[2] = {&o0.x, &o1.x};
#pragma unroll
        for (int e = 0; e < 8; e++) {
            float cj = aj0 * b2f(vj[0][h][e]) + aj1 * b2f(vj[1][h][e]) + aj2 * b2f(vj[2][h][e]);
            float ci = ai0 * b2f(vi[0][h][e]) + ai1 * b2f(vi[1][h][e]) + ai2 * b2f(vi[2][h][e]);
            op[e >> 2][e & 3] = (w0 * cj + w1 * ci) * g;
        }
        reinterpret_cast<float4*>(dst + h * 8)[0] = o0;
        reinterpret_cast<float4*>(dst + h * 8)[1] = o1;
    }
}

// ---------------- launch ----------------
extern "C" void kernel_launch(void* const* d_in, const int* in_sizes, int n_in,
                              void* d_out, int out_size, void* d_ws, size_t ws_size,
                              hipStream_t stream) {
    const float* hs      = (const float*)d_in[0];
    const float* adv     = (const float*)d_in[1];
    const int*   adv_ids = (const int*)d_in[2];
    const int*   ptr_ids = (const int*)d_in[3];
    const float* Wqj = (const float*)d_in[4];
    const float* Wkj = (const float*)d_in[5];
    const float* Wvj = (const float*)d_in[6];
    const float* Wqi = (const float*)d_in[7];
    const float* Wki = (const float*)d_in[8];
    const float* Wvi = (const float*)d_in[9];
    const float* Wout = (const float*)d_in[10];
    const float* gain = (const float*)d_in[11];
    const float* council = (const float*)d_in[12];
    float* out = (float*)d_out;

    const size_t WN  = (size_t)HH * HH;
    const size_t NHb = (size_t)TT * HH;
    dim3 blk(256);

    auto cvt = [&](const float* s, unsigned short* d, size_t n) {
        int n4 = (int)(n / 4);
        cvt_f32_bf16_k<<<dim3(n4 / 256), blk, 0, stream>>>((const float4*)s, (ushort4*)d, n4);
    };

    // ---- weight buffers: Wkv pack 8MB + WoutB 2MB + 6 transposes 12MB = 22 MB ----
    char* ws = (char*)d_ws;
    unsigned short* Wkv   = (unsigned short*)ws;  ws += WN * 4 * 2;   // [Mj|Vj2|Mi|Vi2]
    unsigned short* WoutB = (unsigned short*)ws;  ws += WN * 2;
    unsigned short* WT    = (unsigned short*)ws;  ws += WN * 6 * 2;   // qjT kjT qiT kiT vjT viT

    cvt(Wout, WoutB, WN);
    TrArgs ta;
    ta.s[0] = Wqj; ta.d[0] = WT;
    ta.s[1] = Wkj; ta.d[1] = WT + WN;
    ta.s[2] = Wqi; ta.d[2] = WT + 2 * WN;
    ta.s[3] = Wki; ta.d[3] = WT + 3 * WN;
    ta.s[4] = Wvj; ta.d[4] = WT + 4 * WN;
    ta.s[5] = Wvi; ta.d[5] = WT + 5 * WN;
    transp6_cvt_k<<<dim3(32, 32, 6), blk, 0, stream>>>(ta);

    // folds: Mj = WqjT @ WkjT^T, Vj2 = Wout @ WvjT^T, Mi, Vi2  (all 1024^3)
    FoldArgs fa;
    fa.A[0] = WT;          fa.B[0] = WT + WN;     fa.D[0] = Wkv;            // Mj
    fa.A[1] = WoutB;       fa.B[1] = WT + 4 * WN; fa.D[1] = Wkv + WN;       // Vj2
    fa.A[2] = WT + 2 * WN; fa.B[2] = WT + 3 * WN; fa.D[2] = Wkv + 2 * WN;   // Mi
    fa.A[3] = WoutB;       fa.B[3] = WT + 5 * WN; fa.D[3] = Wkv + 3 * WN;   // Vi2
    gemm_fold4<<<dim3(8, 8, 4), blk, 0, stream>>>(fa);

    const size_t full_need = (size_t)(24 * 1024 * 1024) + (NHb * BB) * 2
                           + (size_t)16384 * 4096 * 2;   // advb + KVb ≈ 184 MB

    if (ws_size >= full_need) {
        unsigned short* advb = (unsigned short*)ws;  ws += NHb * BB * 2;
        unsigned short* KVb  = (unsigned short*)ws;

        cvt(adv, advb, NHb * BB);
        gemm256<<<dim3(16 * 64), dim3(512), 0, stream>>>(advb, Wkv, KVb, 16384, 4096, 1024, 16);
        attn_k<<<dim3((BB * TT) / 4), blk, 0, stream>>>(hs, KVb, adv_ids, ptr_ids,
                                                        council, gain, out);
    } else {
        unsigned short* advb = (unsigned short*)ws;  ws += NHb * 2;
        unsigned short* KVb  = (unsigned short*)ws;

        for (int b = 0; b < BB; b++) {
            cvt(adv + (size_t)b * NHb, advb, NHb);
            gemm256<<<dim3(16 * 16), dim3(512), 0, stream>>>(advb, Wkv, KVb, LL, 4096, 1024, 16);
            attn_k<<<dim3(TT / 4), blk, 0, stream>>>(hs + (size_t)b * NHb, KVb,
                                                     adv_ids + b * LL, ptr_ids + b * TT,
                                                     council, gain, out + (size_t)b * NHb);
        }
    }
}